// Round 4
// baseline (569.948 us; speedup 1.0000x reference)
//
#include <hip/hip_runtime.h>
#include <cstdint>
#include <cstddef>

// ---------------- workspace layout ----------------
// xp  : [32][58][58][256] bf16  (NHWC, spatial halo of zeros)  = 55,115,776 B
// Wb  : [256][2304] bf16 (sign(w) as +-1; k = tap*256 + c)     =  1,179,648 B
// alpha: [256] f32                                              =      1,024 B
#define XP_BYTES 55115776ull
#define WB_OFF   55115776ull
#define AL_OFF   (WB_OFF + 1179648ull)

typedef __bf16 bf16x8 __attribute__((ext_vector_type(8)));
typedef float  f32x4  __attribute__((ext_vector_type(4)));
typedef unsigned short u16x8 __attribute__((ext_vector_type(8)));

static __device__ __forceinline__ unsigned short f2bf(float f) {
  union { float f; unsigned int u; } v; v.f = f;
  unsigned int u = v.u;
  u += 0x7FFFu + ((u >> 16) & 1u);   // RNE
  return (unsigned short)(u >> 16);
}

// ---------------- weight prep: alpha[o] + sign(w) in bf16, k = tap*256+c ----
__global__ void prep_w(const float* __restrict__ w, unsigned short* __restrict__ wb,
                       float* __restrict__ alpha) {
  const int o = blockIdx.x, c = threadIdx.x;
  const float* wr = w + (size_t)(o * 256 + c) * 9;
  float s = 0.f;
#pragma unroll
  for (int tap = 0; tap < 9; ++tap) {
    float v = wr[tap];
    s += fabsf(v);
    unsigned short sg = (v > 0.f) ? 0x3F80u : ((v < 0.f) ? 0xBF80u : 0u);
    wb[(size_t)o * 2304 + tap * 256 + c] = sg;
  }
  __shared__ float red[256];
  red[c] = s;
  __syncthreads();
  for (int d = 128; d > 0; d >>= 1) {
    if (c < d) red[c] += red[c + d];
    __syncthreads();
  }
  if (c == 0) alpha[o] = red[0] * (1.f / 2304.f);
}

// ---------------- halo zeroing: rows 0/57 full width, cols 0/57 rows 1..56 --
__global__ void zero_halo(unsigned short* __restrict__ xp) {
  const int n = blockIdx.x;
  const int t = threadIdx.x;                       // 1024 threads
  uint32_t* base = (uint32_t*)(xp + (size_t)n * 58 * 58 * 256);
  uint32_t* r57 = base + 57 * 7424;                // 58*256 ushort = 7424 u32/row
  for (int i = t; i < 7424; i += 1024) { base[i] = 0; r57[i] = 0; }
  for (int i = t; i < 7168; i += 1024) {           // 56 rows * 128 u32 per col
    const int r = i >> 7, c = i & 127;
    base[(size_t)((r + 1) * 58) * 128 + c] = 0;
    base[(size_t)((r + 1) * 58 + 57) * 128 + c] = 0;
  }
}

// ---------------- x prep: NCHW f32 -> NHWC bf16 (interior), LDS transpose ---
__global__ void prep_x(const float* __restrict__ x, unsigned short* __restrict__ xp) {
  __shared__ unsigned short tile[64 * 256];
  const int bx = blockIdx.x;
  const int n = bx / 49, pt = bx % 49;
  const int p0 = pt * 64;
  const int tid = threadIdx.x;
  const int f = tid & 15;                  // float4 chunk within 64-pixel run
  const int cg = tid >> 4;                 // channel group 0..15
  const float* xn = x + (size_t)n * 256 * 3136 + p0 + f * 4;

#pragma unroll
  for (int i = 0; i < 16; ++i) {
    const int c = cg + i * 16;
    const float4 v = *(const float4*)(xn + (size_t)c * 3136);
    unsigned short b[4] = {f2bf(v.x), f2bf(v.y), f2bf(v.z), f2bf(v.w)};
#pragma unroll
    for (int j = 0; j < 4; ++j) {
      const int pix = f * 4 + j;
      const int cs = c ^ (((pix >> 2) & 3) << 3) ^ (((pix >> 4) & 3) << 5);
      tile[pix * 256 + cs] = b[j];
    }
  }
  __syncthreads();

  const int c8 = (tid & 31) * 8;
  const int psub = tid >> 5;
#pragma unroll
  for (int pass = 0; pass < 8; ++pass) {
    const int pl = psub + pass * 8;
    const int p = p0 + pl;
    const int h = p / 56, w = p % 56;
    const int cs = c8 ^ (((pl >> 2) & 3) << 3) ^ (((pl >> 4) & 3) << 5);
    const u16x8 v = *(const u16x8*)&tile[pl * 256 + cs];
    *(u16x8*)(xp + ((size_t)(n * 58 + h + 1) * 58 + (w + 1)) * 256 + c8) = v;
  }
}

// ---------------- implicit-GEMM conv: C[o][pix] = Wb * Xp ----------------
// Block tile 256(o) x 128(pix); 4 independent waves, wave tile 128x64,
// acc[8][4]. K = 2304 = 72 steps of 32. NO LDS, NO barriers: both operand
// fragments are loaded DIRECTLY global->VGPR (A frag = 16 rows x 64 B = 16
// cachelines; B frag = 16 pixels x 64 B — same line count as a coalesced
// load). Wb (1.15 MB) is L2-resident; per-step working set (16K A + 8K B)
// is L1-sized; xp is XCD-L2-resident via the chunked swizzle (FETCH=102 MB
// measured). One-step register double-buffer (afA/afB, static indexing)
// hides L1/L2 latency; waves free-run so the MFMA pipe is the only shared
// heavy resource.
__global__ __launch_bounds__(256, 2)
void conv_mfma(const unsigned short* __restrict__ xp,
               const unsigned short* __restrict__ wb,
               const float* __restrict__ alpha,
               float* __restrict__ out) {
  const int tid = threadIdx.x;
  const int wave = tid >> 6, lane = tid & 63;
  const int wm = wave & 1, wn = wave >> 1;

  // XCD-chunked pixel-tile swizzle: 784 tiles = 8 XCDs x 98 contiguous tiles
  const int ptile = (blockIdx.x & 7) * 98 + (blockIdx.x >> 3);
  const int pix0 = ptile * 128;

  const int ar = lane & 15, aq = lane >> 4;

  const char* wbB = (const char*)wb;
  const char* xpB = (const char*)xp;

  const char* aP[8];
#pragma unroll
  for (int mi = 0; mi < 8; ++mi)
    aP[mi] = wbB + ((size_t)(wm * 128 + mi * 16 + ar) * 2304 + aq * 8) * 2;

  const char* bP[4];
#pragma unroll
  for (int ni = 0; ni < 4; ++ni) {
    const int pix = pix0 + wn * 64 + ni * 16 + ar;
    const int n = pix / 3136, rem = pix % 3136;
    const int h = rem / 56, w = rem % 56;
    bP[ni] = xpB + (size_t)((n * 58 + h) * 58 + w) * 512 + aq * 16;
  }

  f32x4 acc[8][4];
#pragma unroll
  for (int i = 0; i < 8; ++i)
#pragma unroll
    for (int j = 0; j < 4; ++j) acc[i][j] = (f32x4){0.f, 0.f, 0.f, 0.f};

  bf16x8 afA[8], afB[8], bfA[4], bfB[4];

  // fragment loads for K-step t (t = 0..71): A at +t*64 B; B at tap-structured
  // offset (kh*58+kw)*512 + (t&7)*64.
#define LOADF(AF, BF, t)                                                     \
  do {                                                                       \
    const int _tap = (t) >> 3;                                               \
    const int _kh = (_tap * 11) >> 5;                                        \
    const int _ob = (_kh * 58 + (_tap - _kh * 3)) * 512 + ((t) & 7) * 64;    \
    const int _oa = (t) * 64;                                                \
    _Pragma("unroll")                                                        \
    for (int mi = 0; mi < 8; ++mi)                                           \
      AF[mi] = *(const bf16x8*)(aP[mi] + _oa);                               \
    _Pragma("unroll")                                                        \
    for (int ni = 0; ni < 4; ++ni)                                           \
      BF[ni] = *(const bf16x8*)(bP[ni] + _ob);                               \
  } while (0)

#define MFMAS(AF, BF)                                                        \
  do {                                                                       \
    _Pragma("unroll")                                                        \
    for (int mi = 0; mi < 8; ++mi)                                           \
      _Pragma("unroll")                                                      \
      for (int ni = 0; ni < 4; ++ni)                                         \
        acc[mi][ni] = __builtin_amdgcn_mfma_f32_16x16x32_bf16(               \
            AF[mi], BF[ni], acc[mi][ni], 0, 0, 0);                           \
  } while (0)

  LOADF(afA, bfA, 0);
  for (int t = 0; t < 70; t += 2) {
    LOADF(afB, bfB, t + 1);
    MFMAS(afA, bfA);
    LOADF(afA, bfA, t + 2);
    MFMAS(afB, bfB);
  }
  LOADF(afB, bfB, 71);
  MFMAS(afA, bfA);     // t = 70
  MFMAS(afB, bfB);     // t = 71
#undef LOADF
#undef MFMAS

  // epilogue: D[row=o][col=pix], col=lane&15, row=(lane>>4)*4+r ; scale alpha
  int nc[4], rc[4];
#pragma unroll
  for (int ni = 0; ni < 4; ++ni) {
    const int pix = pix0 + wn * 64 + ni * 16 + ar;
    nc[ni] = pix / 3136; rc[ni] = pix % 3136;
  }
#pragma unroll
  for (int mi = 0; mi < 8; ++mi) {
    const int orow = wm * 128 + mi * 16 + aq * 4;
    float al[4];
#pragma unroll
    for (int r = 0; r < 4; ++r) al[r] = alpha[orow + r];
#pragma unroll
    for (int ni = 0; ni < 4; ++ni) {
      const size_t base = (size_t)nc[ni] * 802816 + (size_t)orow * 3136 + (size_t)rc[ni];
#pragma unroll
      for (int r = 0; r < 4; ++r)
        out[base + (size_t)r * 3136] = acc[mi][ni][r] * al[r];
    }
  }
}

extern "C" void kernel_launch(void* const* d_in, const int* in_sizes, int n_in,
                              void* d_out, int out_size, void* d_ws, size_t ws_size,
                              hipStream_t stream) {
  const float* x = (const float*)d_in[0];
  const float* w = (const float*)d_in[1];
  char* ws = (char*)d_ws;
  unsigned short* xp  = (unsigned short*)ws;
  unsigned short* wbp = (unsigned short*)(ws + WB_OFF);
  float* alpha = (float*)(ws + AL_OFF);
  float* out = (float*)d_out;

  zero_halo<<<32, 1024, 0, stream>>>(xp);
  prep_w<<<256, 256, 0, stream>>>(w, wbp, alpha);
  prep_x<<<32 * 49, 256, 0, stream>>>(x, xp);
  conv_mfma<<<784, 256, 0, stream>>>(xp, wbp, alpha, out);
}

// Round 5
// 303.073 us; speedup vs baseline: 1.8806x; 1.8806x over previous
//
#include <hip/hip_runtime.h>
#include <cstdint>
#include <cstddef>

// ---------------- workspace layout ----------------
// xp  : [32][58][58][256] bf16  (NHWC, spatial halo of zeros)  = 55,115,776 B
// Wb  : [256][2304] bf16 (sign(w) as +-1; k = tap*256 + c)     =  1,179,648 B
// alpha: [256] f32                                              =      1,024 B
#define XP_BYTES 55115776ull
#define WB_OFF   55115776ull
#define AL_OFF   (WB_OFF + 1179648ull)

typedef __bf16 bf16x8 __attribute__((ext_vector_type(8)));
typedef float  f32x4  __attribute__((ext_vector_type(4)));
typedef unsigned short u16x8 __attribute__((ext_vector_type(8)));

static __device__ __forceinline__ unsigned short f2bf(float f) {
  union { float f; unsigned int u; } v; v.f = f;
  unsigned int u = v.u;
  u += 0x7FFFu + ((u >> 16) & 1u);   // RNE
  return (unsigned short)(u >> 16);
}

static __device__ __forceinline__ void async16(void* lds, const void* g) {
  __builtin_amdgcn_global_load_lds(
      (const __attribute__((address_space(1))) unsigned int*)g,
      (__attribute__((address_space(3))) unsigned int*)lds, 16, 0, 0);
}

// ---------------- weight prep: alpha[o] + sign(w) in bf16, k = tap*256+c ----
__global__ void prep_w(const float* __restrict__ w, unsigned short* __restrict__ wb,
                       float* __restrict__ alpha) {
  const int o = blockIdx.x, c = threadIdx.x;
  const float* wr = w + (size_t)(o * 256 + c) * 9;
  float s = 0.f;
#pragma unroll
  for (int tap = 0; tap < 9; ++tap) {
    float v = wr[tap];
    s += fabsf(v);
    unsigned short sg = (v > 0.f) ? 0x3F80u : ((v < 0.f) ? 0xBF80u : 0u);
    wb[(size_t)o * 2304 + tap * 256 + c] = sg;
  }
  __shared__ float red[256];
  red[c] = s;
  __syncthreads();
  for (int d = 128; d > 0; d >>= 1) {
    if (c < d) red[c] += red[c + d];
    __syncthreads();
  }
  if (c == 0) alpha[o] = red[0] * (1.f / 2304.f);
}

// ---------------- halo zeroing ----------------
__global__ void zero_halo(unsigned short* __restrict__ xp) {
  const int n = blockIdx.x;
  const int t = threadIdx.x;                       // 1024 threads
  uint32_t* base = (uint32_t*)(xp + (size_t)n * 58 * 58 * 256);
  uint32_t* r57 = base + 57 * 7424;                // 58*256 ushort = 7424 u32/row
  for (int i = t; i < 7424; i += 1024) { base[i] = 0; r57[i] = 0; }
  for (int i = t; i < 7168; i += 1024) {           // 56 rows * 128 u32 per col
    const int r = i >> 7, c = i & 127;
    base[(size_t)((r + 1) * 58) * 128 + c] = 0;
    base[(size_t)((r + 1) * 58 + 57) * 128 + c] = 0;
  }
}

// ---------------- x prep: NCHW f32 -> NHWC bf16 (interior), LDS transpose ---
__global__ void prep_x(const float* __restrict__ x, unsigned short* __restrict__ xp) {
  __shared__ unsigned short tile[64 * 256];
  const int bx = blockIdx.x;
  const int n = bx / 49, pt = bx % 49;
  const int p0 = pt * 64;
  const int tid = threadIdx.x;
  const int f = tid & 15;
  const int cg = tid >> 4;
  const float* xn = x + (size_t)n * 256 * 3136 + p0 + f * 4;

#pragma unroll
  for (int i = 0; i < 16; ++i) {
    const int c = cg + i * 16;
    const float4 v = *(const float4*)(xn + (size_t)c * 3136);
    unsigned short b[4] = {f2bf(v.x), f2bf(v.y), f2bf(v.z), f2bf(v.w)};
#pragma unroll
    for (int j = 0; j < 4; ++j) {
      const int pix = f * 4 + j;
      const int cs = c ^ (((pix >> 2) & 3) << 3) ^ (((pix >> 4) & 3) << 5);
      tile[pix * 256 + cs] = b[j];
    }
  }
  __syncthreads();

  const int c8 = (tid & 31) * 8;
  const int psub = tid >> 5;
#pragma unroll
  for (int pass = 0; pass < 8; ++pass) {
    const int pl = psub + pass * 8;
    const int p = p0 + pl;
    const int h = p / 56, w = p % 56;
    const int cs = c8 ^ (((pl >> 2) & 3) << 3) ^ (((pl >> 4) & 3) << 5);
    const u16x8 v = *(const u16x8*)&tile[pl * 256 + cs];
    *(u16x8*)(xp + ((size_t)(n * 58 + h + 1) * 58 + (w + 1)) * 256 + c8) = v;
  }
}

// ---------------- implicit-GEMM conv, m201-style 8-phase schedule ----------
// Block 256(o) x 256(pix), 8 waves (wm=wave&1, wn=wave>>1), wave tile 128x64.
// K = 2304 = 36 tiles of BK=64 (2 slices of 32). 18 iterations x 2 K-tiles.
// LDS 128 KiB: buf b in {0,1}: A[b]=[2 ks][256 o][64 B] @ b*32768,
//                              B[b]=[2 ks][256 pix][64 B] @ 65536+b*32768.
// Halves: A_even = o rows with bit6==0 (used by quadrant mh=0), A_odd = bit6==1;
//         B_even = pix with bit5==0 (nh=0), B_odd = bit5==1. Each half-tile
// (16 KB) staged by 16 wave-instructions (8 waves x 2 global_load_lds).
// Phase = {ds_read frags ; stage 1 half ; barrier ; lgkmcnt(0)+sched_barrier ;
// 16 MFMA (setprio) ; [vmcnt(4) at ph4/ph8] ; barrier}. vmcnt never 0 in loop.
// Stage/death audit (phases 1..8 of iter i; T0=2i in buf0, T1=2i+1 in buf1):
//  ph1: stage A_odd(b1,T1)  — prev A_odd(b1) last read ph7 of i-1, lgkm'd+bar.
//  ph2: stage B_even(b1,T1) — prev read ph5 of i-1.
//  ph3: stage A_even(b0,T0+2) — read ph1 this iter.   ph4: B_odd(b0,T0+2) (ph2).
//  ph5: A_odd(b0,T0+2) (ph3). ph6: B_even(b0,T0+2) (ph1). ph7: A_even(b1,T1+2)
//  (ph5). ph8: B_odd(b1,T1+2) (ph6).
// Readiness: vmcnt(4) at ph4 leaves {ph3,ph4} outstanding -> ph1/ph2 stages
// (latest needed for ph5-8) landed; barrier makes it block-wide. vmcnt(4) at
// ph8 leaves {ph7,ph8} -> ph5/ph6 (latest needed for next ph1-4) landed.
// Tail (i=17): stages for tiles 36/37 skipped; ph4 uses vmcnt(0) to cover
// ph1/ph2 (tile-35 halves), ph8 needs nothing.
// Swizzle (rule 21, round-3-verified 0-conflict): stage source chunk
// (lane&3)^((rsub>>1)&3); fragment read pos = aq^((ar>>1)&3).
__global__ __launch_bounds__(512, 1)
void conv_mfma(const unsigned short* __restrict__ xp,
               const unsigned short* __restrict__ wb,
               const float* __restrict__ alpha,
               float* __restrict__ out) {
  __shared__ __align__(16) char lds[131072];

  const int tid = threadIdx.x;
  const int wave = tid >> 6, lane = tid & 63;
  const int wm = wave & 1, wn = wave >> 1;          // wn 0..3

  // XCD-chunked pixel-tile swizzle: 392 = 8 XCDs x 49 contiguous tiles
  const int ptile = (blockIdx.x & 7) * 49 + (blockIdx.x >> 3);
  const int pix0 = ptile * 256;

  const int ar = lane & 15, aq = lane >> 4;
  const int rpos = (aq ^ ((ar >> 1) & 3)) * 16;     // fragment-read byte pos
  const int rsub = lane >> 2;
  const int chunkS = (lane & 3) ^ ((rsub >> 1) & 3);  // stage source chunk

  const char* wbB = (const char*)wb;
  const char* xpB = (const char*)xp;

  // ---- stage pointer setup: instr j of this wave covers (ks, 16-row group g)
  const char* aSrc[2]; int aDst[2];
  const char* bSrcP[2][2]; int bDst[2];
#pragma unroll
  for (int j = 0; j < 2; ++j) {
    const int idx = j * 8 + wave;        // 0..15
    const int ksS = idx & 1, grp = idx >> 1;   // grp 0..7
    const int rowNP = (grp & 3) * 16 + ((grp >> 2) << 7);   // A rows, parity 0
    aSrc[j] = wbB + (size_t)(rowNP + rsub) * 4608 + ksS * 64 + chunkS * 16;
    aDst[j] = ksS * 16384 + rowNP * 64;
    const int pixNP = (grp >> 1) * 64 + (grp & 1) * 16;     // B pix, parity 0
#pragma unroll
    for (int par = 0; par < 2; ++par) {
      const int pix = pix0 + pixNP + par * 32 + rsub;
      const int n = pix / 3136, rem = pix % 3136;
      const int h = rem / 56, w = rem % 56;
      bSrcP[par][j] = xpB + (size_t)((n * 58 + h) * 58 + w) * 512 + ksS * 64 + chunkS * 16;
    }
    bDst[j] = 65536 + ksS * 16384 + pixNP * 64;
  }

  f32x4 acc[8][4];
#pragma unroll
  for (int i = 0; i < 8; ++i)
#pragma unroll
    for (int j = 0; j < 4; ++j) acc[i][j] = (f32x4){0.f, 0.f, 0.f, 0.f};

  bf16x8 af[4][2], bfE[2][2], bfO[2][2];

  auto stageA = [&](int b, int T, int par) {
    const size_t so = (size_t)par * 294912 + (size_t)T * 128;
    const int dof = par * 4096 + b * 32768;
#pragma unroll
    for (int j = 0; j < 2; ++j)
      async16(lds + aDst[j] + dof, aSrc[j] + so);
  };
  auto stageB = [&](int b, int T, int par) {
    const int tap = T >> 2;
    const int kh = (tap * 11) >> 5, kw = tap - kh * 3;
    const int ob = (kh * 58 + kw) * 512 + (T & 3) * 128;
    const int dof = par * 2048 + b * 32768;
#pragma unroll
    for (int j = 0; j < 2; ++j)
      async16(lds + bDst[j] + dof, bSrcP[par][j] + ob);
  };
  auto readA = [&](int b, int mh) {
    const char* base = lds + b * 32768;
#pragma unroll
    for (int q = 0; q < 4; ++q)
#pragma unroll
      for (int ks = 0; ks < 2; ++ks)
        af[q][ks] = *(const bf16x8*)(base + ks * 16384 +
                      (wm * 128 + mh * 64 + q * 16 + ar) * 64 + rpos);
  };
  auto readB = [&](int b, int nh, bf16x8 (*bf)[2]) {
    const char* base = lds + 65536 + b * 32768;
#pragma unroll
    for (int q = 0; q < 2; ++q)
#pragma unroll
      for (int ks = 0; ks < 2; ++ks)
        bf[q][ks] = *(const bf16x8*)(base + ks * 16384 +
                      (wn * 64 + nh * 32 + q * 16 + ar) * 64 + rpos);
  };
  auto mmaQ = [&](int mh, int nh, bf16x8 (*bf)[2]) {
    __builtin_amdgcn_s_setprio(1);
#pragma unroll
    for (int ks = 0; ks < 2; ++ks)
#pragma unroll
      for (int q = 0; q < 4; ++q)
#pragma unroll
        for (int r = 0; r < 2; ++r)
          acc[mh * 4 + q][nh * 2 + r] = __builtin_amdgcn_mfma_f32_16x16x32_bf16(
              af[q][ks], bf[r][ks], acc[mh * 4 + q][nh * 2 + r], 0, 0, 0);
    __builtin_amdgcn_s_setprio(0);
  };

#define PH_SYNC                                          \
  asm volatile("" ::: "memory");                         \
  __builtin_amdgcn_s_barrier();                          \
  asm volatile("s_waitcnt lgkmcnt(0)" ::: "memory");     \
  __builtin_amdgcn_sched_barrier(0);
#define PH_END                                           \
  asm volatile("" ::: "memory");                         \
  __builtin_amdgcn_s_barrier();

  // ---- prologue: tile 0 -> buf0 (4 halves), tile 1 A_even/B_odd -> buf1
  stageA(0, 0, 0); stageB(0, 0, 1); stageA(0, 0, 1); stageB(0, 0, 0);
  stageA(1, 1, 0); stageB(1, 1, 1);
  asm volatile("s_waitcnt vmcnt(4)" ::: "memory");   // tile-0 halves landed
  PH_END;

  for (int i = 0; i < 18; ++i) {
    const int T0 = 2 * i, T1 = 2 * i + 1;
    const bool pf = (i < 17);
    // ph1: Q(0,0) buf0
    readA(0, 0); readB(0, 0, bfE);
    stageA(1, T1, 1);
    PH_SYNC; mmaQ(0, 0, bfE); PH_END;
    // ph2: Q(0,1)
    readB(0, 1, bfO);
    stageB(1, T1, 0);
    PH_SYNC; mmaQ(0, 1, bfO); PH_END;
    // ph3: Q(1,1)
    readA(0, 1);
    if (pf) stageA(0, T0 + 2, 0);
    PH_SYNC; mmaQ(1, 1, bfO); PH_END;
    // ph4: Q(1,0) + vmcnt gate for ph5-8
    if (pf) stageB(0, T0 + 2, 1);
    PH_SYNC; mmaQ(1, 0, bfE);
    if (pf) { asm volatile("s_waitcnt vmcnt(4)" ::: "memory"); }
    else    { asm volatile("s_waitcnt vmcnt(0)" ::: "memory"); }
    PH_END;
    // ph5: Q(0,0) buf1
    readA(1, 0); readB(1, 0, bfE);
    if (pf) stageA(0, T0 + 2, 1);
    PH_SYNC; mmaQ(0, 0, bfE); PH_END;
    // ph6: Q(0,1)
    readB(1, 1, bfO);
    if (pf) stageB(0, T0 + 2, 0);
    PH_SYNC; mmaQ(0, 1, bfO); PH_END;
    // ph7: Q(1,1)
    readA(1, 1);
    if (pf) stageA(1, T1 + 2, 0);
    PH_SYNC; mmaQ(1, 1, bfO); PH_END;
    // ph8: Q(1,0) + vmcnt gate for next ph1-4
    if (pf) stageB(1, T1 + 2, 1);
    PH_SYNC; mmaQ(1, 0, bfE);
    if (pf) { asm volatile("s_waitcnt vmcnt(4)" ::: "memory"); }
    PH_END;
  }
#undef PH_SYNC
#undef PH_END

  // epilogue: D[row=o][col=pix], col=lane&15, row=(lane>>4)*4+r ; scale alpha
  int nc[4], rc[4];
#pragma unroll
  for (int ni = 0; ni < 4; ++ni) {
    const int pix = pix0 + wn * 64 + ni * 16 + ar;
    nc[ni] = pix / 3136; rc[ni] = pix % 3136;
  }
#pragma unroll
  for (int mi = 0; mi < 8; ++mi) {
    const int orow = wm * 128 + mi * 16 + aq * 4;
    float al[4];
#pragma unroll
    for (int r = 0; r < 4; ++r) al[r] = alpha[orow + r];
#pragma unroll
    for (int ni = 0; ni < 4; ++ni) {
      const size_t base = (size_t)nc[ni] * 802816 + (size_t)orow * 3136 + (size_t)rc[ni];
#pragma unroll
      for (int r = 0; r < 4; ++r)
        out[base + (size_t)r * 3136] = acc[mi][ni][r] * al[r];
    }
  }
}

extern "C" void kernel_launch(void* const* d_in, const int* in_sizes, int n_in,
                              void* d_out, int out_size, void* d_ws, size_t ws_size,
                              hipStream_t stream) {
  const float* x = (const float*)d_in[0];
  const float* w = (const float*)d_in[1];
  char* ws = (char*)d_ws;
  unsigned short* xp  = (unsigned short*)ws;
  unsigned short* wbp = (unsigned short*)(ws + WB_OFF);
  float* alpha = (float*)(ws + AL_OFF);
  float* out = (float*)d_out;

  zero_halo<<<32, 1024, 0, stream>>>(xp);
  prep_w<<<256, 256, 0, stream>>>(w, wbp, alpha);
  prep_x<<<32 * 49, 256, 0, stream>>>(x, xp);
  conv_mfma<<<392, 512, 0, stream>>>(xp, wbp, alpha, out);
}

// Round 7
// 300.840 us; speedup vs baseline: 1.8945x; 1.0074x over previous
//
#include <hip/hip_runtime.h>
#include <cstdint>
#include <cstddef>

// ---------------- workspace layout ----------------
// xp  : [32][58][58][256] bf16  (NHWC, spatial halo of zeros)  = 55,115,776 B
// Wb  : [256][2304] bf16 (sign(w) as +-1; k = tap*256 + c)     =  1,179,648 B
// alpha: [256] f32                                              =      1,024 B
#define XP_BYTES 55115776ull
#define WB_OFF   55115776ull
#define AL_OFF   (WB_OFF + 1179648ull)

typedef __bf16 bf16x8 __attribute__((ext_vector_type(8)));
typedef float  f32x4  __attribute__((ext_vector_type(4)));
typedef unsigned short u16x8 __attribute__((ext_vector_type(8)));

static __device__ __forceinline__ unsigned short f2bf(float f) {
  union { float f; unsigned int u; } v; v.f = f;
  unsigned int u = v.u;
  u += 0x7FFFu + ((u >> 16) & 1u);   // RNE
  return (unsigned short)(u >> 16);
}

static __device__ __forceinline__ void async16(void* lds, const void* g) {
  __builtin_amdgcn_global_load_lds(
      (const __attribute__((address_space(1))) unsigned int*)g,
      (__attribute__((address_space(3))) unsigned int*)lds, 16, 0, 0);
}

// ---------------- weight prep: alpha[o] + sign(w) in bf16, k = tap*256+c ----
__global__ void prep_w(const float* __restrict__ w, unsigned short* __restrict__ wb,
                       float* __restrict__ alpha) {
  const int o = blockIdx.x, c = threadIdx.x;
  const float* wr = w + (size_t)(o * 256 + c) * 9;
  float s = 0.f;
#pragma unroll
  for (int tap = 0; tap < 9; ++tap) {
    float v = wr[tap];
    s += fabsf(v);
    unsigned short sg = (v > 0.f) ? 0x3F80u : ((v < 0.f) ? 0xBF80u : 0u);
    wb[(size_t)o * 2304 + tap * 256 + c] = sg;
  }
  __shared__ float red[256];
  red[c] = s;
  __syncthreads();
  for (int d = 128; d > 0; d >>= 1) {
    if (c < d) red[c] += red[c + d];
    __syncthreads();
  }
  if (c == 0) alpha[o] = red[0] * (1.f / 2304.f);
}

// ---------------- halo zeroing ----------------
__global__ void zero_halo(unsigned short* __restrict__ xp) {
  const int n = blockIdx.x;
  const int t = threadIdx.x;                       // 1024 threads
  uint32_t* base = (uint32_t*)(xp + (size_t)n * 58 * 58 * 256);
  uint32_t* r57 = base + 57 * 7424;                // 58*256 ushort = 7424 u32/row
  for (int i = t; i < 7424; i += 1024) { base[i] = 0; r57[i] = 0; }
  for (int i = t; i < 7168; i += 1024) {           // 56 rows * 128 u32 per col
    const int r = i >> 7, c = i & 127;
    base[(size_t)((r + 1) * 58) * 128 + c] = 0;
    base[(size_t)((r + 1) * 58 + 57) * 128 + c] = 0;
  }
}

// ---------------- x prep: NCHW f32 -> NHWC bf16 (interior), LDS transpose ---
__global__ void prep_x(const float* __restrict__ x, unsigned short* __restrict__ xp) {
  __shared__ unsigned short tile[64 * 256];
  const int bx = blockIdx.x;
  const int n = bx / 49, pt = bx % 49;
  const int p0 = pt * 64;
  const int tid = threadIdx.x;
  const int f = tid & 15;
  const int cg = tid >> 4;
  const float* xn = x + (size_t)n * 256 * 3136 + p0 + f * 4;

#pragma unroll
  for (int i = 0; i < 16; ++i) {
    const int c = cg + i * 16;
    const float4 v = *(const float4*)(xn + (size_t)c * 3136);
    unsigned short b[4] = {f2bf(v.x), f2bf(v.y), f2bf(v.z), f2bf(v.w)};
#pragma unroll
    for (int j = 0; j < 4; ++j) {
      const int pix = f * 4 + j;
      const int cs = c ^ (((pix >> 2) & 3) << 3) ^ (((pix >> 4) & 3) << 5);
      tile[pix * 256 + cs] = b[j];
    }
  }
  __syncthreads();

  const int c8 = (tid & 31) * 8;
  const int psub = tid >> 5;
#pragma unroll
  for (int pass = 0; pass < 8; ++pass) {
    const int pl = psub + pass * 8;
    const int p = p0 + pl;
    const int h = p / 56, w = p % 56;
    const int cs = c8 ^ (((pl >> 2) & 3) << 3) ^ (((pl >> 4) & 3) << 5);
    const u16x8 v = *(const u16x8*)&tile[pl * 256 + cs];
    *(u16x8*)(xp + ((size_t)(n * 58 + h + 1) * 58 + (w + 1)) * 256 + c8) = v;
  }
}

// ---------------- implicit-GEMM conv, 8-phase + safe read-ahead ----------
// Geometry/staging/gating identical to round 5 (proven correct):
// Block 256(o) x 256(pix), 8 waves, wave tile 128x64, BK=64, 2 K-tiles/iter,
// LDS 128 KiB double-buffered, one stage-half per phase, counted vmcnt(4)
// at ph4/ph8 only, swizzle = pre-permuted source chunk + read XOR.
//
// LESSON (round 6 failure): s_waitcnt vmcnt(N) is PER-WAVE. Half-tiles are
// staged cooperatively by all 8 waves, so a read of a half-tile is only safe
// after a BARRIER that every wave reached after its own vmcnt gate. Reads
// placed between a wave's vmcnt and the barrier raced other waves' staging.
//
// Read placement (all audited):
//  ph1-top  af(b0,ev)+bfE(b0): staged ph3/ph6(i-1); gate ph8(i-1) vmcnt4
//           [leaves ph7,ph8 outstanding -> ph3..ph6 landed] + PH_END barrier.
//  end-ph1  bfO(b0): staged ph4(i-1); gate ph8(i-1)+barrier (passed). safe.
//  end-ph2  af(b0,odd): staged ph5(i-1); gate ph8(i-1)+barrier. safe.
//  ph5-top  af(b1,ev)+bfE(b1): staged ph7(i-1)/ph2(i); gate ph4(i) vmcnt4
//           [leaves ph3,ph4 outstanding -> ph7(i-1),ph2(i) landed] + barrier.
//  end-ph5  bfO(b1): staged ph8(i-1); gate ph4(i)+barrier. safe.
//  end-ph6  af(b1,odd): staged ph1(i); gate ph4(i)+barrier. safe.
// In-phase LDS write/read disjointness (waves skew at most one phase window):
//  ph1 writes A_odd(b1), reads B_odd(b0); ph2 writes B_ev(b1), reads A_odd(b0);
//  ph5 writes A_odd(b0), reads A_ev(b1)/B_ev(b1)/B_odd(b1); ph6 writes
//  B_ev(b0), reads A_odd(b1). No overlap. Register WAR safe (MFMA latches
//  operands at issue; reads follow MFMAs in program order).
// Tail i=17: no stages after ph2; ph4 gate = vmcnt(0) covers ph7/ph8(16) and
//  ph1/ph2(17) for the remaining reads.
__global__ __launch_bounds__(512, 1)
void conv_mfma(const unsigned short* __restrict__ xp,
               const unsigned short* __restrict__ wb,
               const float* __restrict__ alpha,
               float* __restrict__ out) {
  __shared__ __align__(16) char lds[131072];

  const int tid = threadIdx.x;
  const int wave = tid >> 6, lane = tid & 63;
  const int wm = wave & 1, wn = wave >> 1;          // wn 0..3

  // XCD-chunked pixel-tile swizzle: 392 = 8 XCDs x 49 contiguous tiles
  const int ptile = (blockIdx.x & 7) * 49 + (blockIdx.x >> 3);
  const int pix0 = ptile * 256;

  const int ar = lane & 15, aq = lane >> 4;
  const int rpos = (aq ^ ((ar >> 1) & 3)) * 16;     // fragment-read byte pos
  const int rsub = lane >> 2;
  const int chunkS = (lane & 3) ^ ((rsub >> 1) & 3);  // stage source chunk

  const char* wbB = (const char*)wb;
  const char* xpB = (const char*)xp;

  // ---- stage pointer setup: instr j of this wave covers (ks, 16-row group g)
  const char* aSrc[2]; int aDst[2];
  const char* bSrcP[2][2]; int bDst[2];
#pragma unroll
  for (int j = 0; j < 2; ++j) {
    const int idx = j * 8 + wave;        // 0..15
    const int ksS = idx & 1, grp = idx >> 1;   // grp 0..7
    const int rowNP = (grp & 3) * 16 + ((grp >> 2) << 7);   // A rows, parity 0
    aSrc[j] = wbB + (size_t)(rowNP + rsub) * 4608 + ksS * 64 + chunkS * 16;
    aDst[j] = ksS * 16384 + rowNP * 64;
    const int pixNP = (grp >> 1) * 64 + (grp & 1) * 16;     // B pix, parity 0
#pragma unroll
    for (int par = 0; par < 2; ++par) {
      const int pix = pix0 + pixNP + par * 32 + rsub;
      const int n = pix / 3136, rem = pix % 3136;
      const int h = rem / 56, w = rem % 56;
      bSrcP[par][j] = xpB + (size_t)((n * 58 + h) * 58 + w) * 512 + ksS * 64 + chunkS * 16;
    }
    bDst[j] = 65536 + ksS * 16384 + pixNP * 64;
  }

  f32x4 acc[8][4];
#pragma unroll
  for (int i = 0; i < 8; ++i)
#pragma unroll
    for (int j = 0; j < 4; ++j) acc[i][j] = (f32x4){0.f, 0.f, 0.f, 0.f};

  bf16x8 af[4][2], bfE[2][2], bfO[2][2];

  auto stageA = [&](int b, int T, int par) {
    const size_t so = (size_t)par * 294912 + (size_t)T * 128;
    const int dof = par * 4096 + b * 32768;
#pragma unroll
    for (int j = 0; j < 2; ++j)
      async16(lds + aDst[j] + dof, aSrc[j] + so);
  };
  auto stageB = [&](int b, int T, int par) {
    const int tap = T >> 2;
    const int kh = (tap * 11) >> 5, kw = tap - kh * 3;
    const int ob = (kh * 58 + kw) * 512 + (T & 3) * 128;
    const int dof = par * 2048 + b * 32768;
#pragma unroll
    for (int j = 0; j < 2; ++j)
      async16(lds + bDst[j] + dof, bSrcP[par][j] + ob);
  };
  auto readA = [&](int b, int mh) {
    const char* base = lds + b * 32768;
#pragma unroll
    for (int q = 0; q < 4; ++q)
#pragma unroll
      for (int ks = 0; ks < 2; ++ks)
        af[q][ks] = *(const bf16x8*)(base + ks * 16384 +
                      (wm * 128 + mh * 64 + q * 16 + ar) * 64 + rpos);
  };
  auto readB = [&](int b, int nh, bf16x8 (*bf)[2]) {
    const char* base = lds + 65536 + b * 32768;
#pragma unroll
    for (int q = 0; q < 2; ++q)
#pragma unroll
      for (int ks = 0; ks < 2; ++ks)
        bf[q][ks] = *(const bf16x8*)(base + ks * 16384 +
                      (wn * 64 + nh * 32 + q * 16 + ar) * 64 + rpos);
  };
  auto mmaQ = [&](int mh, int nh, bf16x8 (*bf)[2]) {
    __builtin_amdgcn_s_setprio(1);
#pragma unroll
    for (int ks = 0; ks < 2; ++ks)
#pragma unroll
      for (int q = 0; q < 4; ++q)
#pragma unroll
        for (int r = 0; r < 2; ++r)
          acc[mh * 4 + q][nh * 2 + r] = __builtin_amdgcn_mfma_f32_16x16x32_bf16(
              af[q][ks], bf[r][ks], acc[mh * 4 + q][nh * 2 + r], 0, 0, 0);
    __builtin_amdgcn_s_setprio(0);
  };

#define PH_SYNC                                          \
  asm volatile("" ::: "memory");                         \
  __builtin_amdgcn_s_barrier();                          \
  asm volatile("s_waitcnt lgkmcnt(0)" ::: "memory");     \
  __builtin_amdgcn_sched_barrier(0);
#define PH_END                                           \
  asm volatile("" ::: "memory");                         \
  __builtin_amdgcn_s_barrier();

  // ---- prologue: tile 0 -> buf0 (4 halves), tile 1 A_even/B_odd -> buf1.
  // vmcnt(4) leaves the last 2 stages outstanding -> tile-0 halves landed
  // (this wave); PH_END barrier makes it block-wide. Reads happen at ph1-top.
  stageA(0, 0, 0); stageB(0, 0, 1); stageA(0, 0, 1); stageB(0, 0, 0);
  stageA(1, 1, 0); stageB(1, 1, 1);
  asm volatile("s_waitcnt vmcnt(4)" ::: "memory");
  PH_END;

  for (int i = 0; i < 18; ++i) {
    const int T0 = 2 * i, T1 = 2 * i + 1;
    const bool pf = (i < 17);
    // ph1: top-reads af(b0,ev)+bfE(b0) ; Q(0,0) buf0 ; end-read bfO(b0)
    readA(0, 0); readB(0, 0, bfE);
    stageA(1, T1, 1);
    PH_SYNC; mmaQ(0, 0, bfE);
    readB(0, 1, bfO);
    PH_END;
    // ph2: Q(0,1) ; end-read af(b0,odd)
    stageB(1, T1, 0);
    PH_SYNC; mmaQ(0, 1, bfO);
    readA(0, 1);
    PH_END;
    // ph3: Q(1,1)
    if (pf) stageA(0, T0 + 2, 0);
    PH_SYNC; mmaQ(1, 1, bfO); PH_END;
    // ph4: Q(1,0) ; per-wave vmcnt gate, block-wide after PH_END
    if (pf) stageB(0, T0 + 2, 1);
    PH_SYNC; mmaQ(1, 0, bfE);
    if (pf) { asm volatile("s_waitcnt vmcnt(4)" ::: "memory"); }
    else    { asm volatile("s_waitcnt vmcnt(0)" ::: "memory"); }
    PH_END;
    // ph5: top-reads af(b1,ev)+bfE(b1) ; Q(0,0) buf1 ; end-read bfO(b1)
    readA(1, 0); readB(1, 0, bfE);
    if (pf) stageA(0, T0 + 2, 1);
    PH_SYNC; mmaQ(0, 0, bfE);
    readB(1, 1, bfO);
    PH_END;
    // ph6: Q(0,1) ; end-read af(b1,odd)
    if (pf) stageB(0, T0 + 2, 0);
    PH_SYNC; mmaQ(0, 1, bfO);
    readA(1, 1);
    PH_END;
    // ph7: Q(1,1)
    if (pf) stageA(1, T1 + 2, 0);
    PH_SYNC; mmaQ(1, 1, bfO); PH_END;
    // ph8: Q(1,0) ; per-wave vmcnt gate, block-wide after PH_END
    if (pf) stageB(1, T1 + 2, 1);
    PH_SYNC; mmaQ(1, 0, bfE);
    if (pf) { asm volatile("s_waitcnt vmcnt(4)" ::: "memory"); }
    PH_END;
  }
#undef PH_SYNC
#undef PH_END

  // epilogue: D[row=o][col=pix], col=lane&15, row=(lane>>4)*4+r ; scale alpha
  int nc[4], rc[4];
#pragma unroll
  for (int ni = 0; ni < 4; ++ni) {
    const int pix = pix0 + wn * 64 + ni * 16 + ar;
    nc[ni] = pix / 3136; rc[ni] = pix % 3136;
  }
#pragma unroll
  for (int mi = 0; mi < 8; ++mi) {
    const int orow = wm * 128 + mi * 16 + aq * 4;
    float al[4];
#pragma unroll
    for (int r = 0; r < 4; ++r) al[r] = alpha[orow + r];
#pragma unroll
    for (int ni = 0; ni < 4; ++ni) {
      const size_t base = (size_t)nc[ni] * 802816 + (size_t)orow * 3136 + (size_t)rc[ni];
#pragma unroll
      for (int r = 0; r < 4; ++r)
        out[base + (size_t)r * 3136] = acc[mi][ni][r] * al[r];
    }
  }
}

extern "C" void kernel_launch(void* const* d_in, const int* in_sizes, int n_in,
                              void* d_out, int out_size, void* d_ws, size_t ws_size,
                              hipStream_t stream) {
  const float* x = (const float*)d_in[0];
  const float* w = (const float*)d_in[1];
  char* ws = (char*)d_ws;
  unsigned short* xp  = (unsigned short*)ws;
  unsigned short* wbp = (unsigned short*)(ws + WB_OFF);
  float* alpha = (float*)(ws + AL_OFF);
  float* out = (float*)d_out;

  zero_halo<<<32, 1024, 0, stream>>>(xp);
  prep_w<<<256, 256, 0, stream>>>(w, wbp, alpha);
  prep_x<<<32 * 49, 256, 0, stream>>>(x, xp);
  conv_mfma<<<392, 512, 0, stream>>>(xp, wbp, alpha, out);
}

// Round 8
// 296.469 us; speedup vs baseline: 1.9225x; 1.0147x over previous
//
#include <hip/hip_runtime.h>
#include <cstdint>
#include <cstddef>

// ---------------- workspace layout ----------------
// xp  : [32][58][58][256] bf16  (NHWC, spatial halo of zeros)  = 55,115,776 B
// Wb  : [256][2304] bf16 (sign(w) as +-1; k = tap*256 + c)     =  1,179,648 B
// alpha: [256] f32                                              =      1,024 B
#define XP_BYTES 55115776ull
#define WB_OFF   55115776ull
#define AL_OFF   (WB_OFF + 1179648ull)

typedef __bf16 bf16x8 __attribute__((ext_vector_type(8)));
typedef float  f32x4  __attribute__((ext_vector_type(4)));
typedef unsigned short u16x8 __attribute__((ext_vector_type(8)));

static __device__ __forceinline__ unsigned short f2bf(float f) {
  union { float f; unsigned int u; } v; v.f = f;
  unsigned int u = v.u;
  u += 0x7FFFu + ((u >> 16) & 1u);   // RNE
  return (unsigned short)(u >> 16);
}

static __device__ __forceinline__ void async16(void* lds, const void* g) {
  __builtin_amdgcn_global_load_lds(
      (const __attribute__((address_space(1))) unsigned int*)g,
      (__attribute__((address_space(3))) unsigned int*)lds, 16, 0, 0);
}

// ---------------- weight prep: alpha[o] + sign(w) in bf16, k = tap*256+c ----
__global__ void prep_w(const float* __restrict__ w, unsigned short* __restrict__ wb,
                       float* __restrict__ alpha) {
  const int o = blockIdx.x, c = threadIdx.x;
  const float* wr = w + (size_t)(o * 256 + c) * 9;
  float s = 0.f;
#pragma unroll
  for (int tap = 0; tap < 9; ++tap) {
    float v = wr[tap];
    s += fabsf(v);
    unsigned short sg = (v > 0.f) ? 0x3F80u : ((v < 0.f) ? 0xBF80u : 0u);
    wb[(size_t)o * 2304 + tap * 256 + c] = sg;
  }
  __shared__ float red[256];
  red[c] = s;
  __syncthreads();
  for (int d = 128; d > 0; d >>= 1) {
    if (c < d) red[c] += red[c + d];
    __syncthreads();
  }
  if (c == 0) alpha[o] = red[0] * (1.f / 2304.f);
}

// ---------------- halo zeroing ----------------
__global__ void zero_halo(unsigned short* __restrict__ xp) {
  const int n = blockIdx.x;
  const int t = threadIdx.x;                       // 1024 threads
  uint32_t* base = (uint32_t*)(xp + (size_t)n * 58 * 58 * 256);
  uint32_t* r57 = base + 57 * 7424;                // 58*256 ushort = 7424 u32/row
  for (int i = t; i < 7424; i += 1024) { base[i] = 0; r57[i] = 0; }
  for (int i = t; i < 7168; i += 1024) {           // 56 rows * 128 u32 per col
    const int r = i >> 7, c = i & 127;
    base[(size_t)((r + 1) * 58) * 128 + c] = 0;
    base[(size_t)((r + 1) * 58 + 57) * 128 + c] = 0;
  }
}

// ---------------- x prep: NCHW f32 -> NHWC bf16 (interior), LDS transpose ---
__global__ void prep_x(const float* __restrict__ x, unsigned short* __restrict__ xp) {
  __shared__ unsigned short tile[64 * 256];
  const int bx = blockIdx.x;
  const int n = bx / 49, pt = bx % 49;
  const int p0 = pt * 64;
  const int tid = threadIdx.x;
  const int f = tid & 15;
  const int cg = tid >> 4;
  const float* xn = x + (size_t)n * 256 * 3136 + p0 + f * 4;

#pragma unroll
  for (int i = 0; i < 16; ++i) {
    const int c = cg + i * 16;
    const float4 v = *(const float4*)(xn + (size_t)c * 3136);
    unsigned short b[4] = {f2bf(v.x), f2bf(v.y), f2bf(v.z), f2bf(v.w)};
#pragma unroll
    for (int j = 0; j < 4; ++j) {
      const int pix = f * 4 + j;
      const int cs = c ^ (((pix >> 2) & 3) << 3) ^ (((pix >> 4) & 3) << 5);
      tile[pix * 256 + cs] = b[j];
    }
  }
  __syncthreads();

  const int c8 = (tid & 31) * 8;
  const int psub = tid >> 5;
#pragma unroll
  for (int pass = 0; pass < 8; ++pass) {
    const int pl = psub + pass * 8;
    const int p = p0 + pl;
    const int h = p / 56, w = p % 56;
    const int cs = c8 ^ (((pl >> 2) & 3) << 3) ^ (((pl >> 4) & 3) << 5);
    const u16x8 v = *(const u16x8*)&tile[pl * 256 + cs];
    *(u16x8*)(xp + ((size_t)(n * 58 + h + 1) * 58 + (w + 1)) * 256 + c8) = v;
  }
}

// ---------------- implicit-GEMM conv, 8-phase, fully-overlapped reads -------
// Geometry/staging identical to rounds 5/7 (proven correct). New: every
// fragment-read set has an EARLIER vmcnt gate (+ the barrier that follows it)
// so it can be issued after a LATER phase's MFMA cluster instead of at a
// phase top behind lgkmcnt(0). Rule (round-6 lesson): a read of a
// cooperatively-staged half is legal only after {every wave's own vmcnt
// covering that stage} + {a subsequent s_barrier}.
//
// Per-wave outstanding-stage ledger (2 gload_lds per stage call):
//  gates: end-ph3 vmcnt(2)  -> drains ph7,ph8(i-1), ph1,ph2(i)
//         end-ph7 vmcnt(8)  -> drains ph3(i)
//         end-ph8 vmcnt(4)  -> drains ph4,ph5,ph6(i)   (leaves ph7,ph8)
//  (prologue: 12 outstanding, vmcnt(4) drains the 4 tile-0 halves)
// Read-set audit (staged-at -> gate -> barrier -> read position):
//  bfE(0):  ph6(i-1) -> ph8(i-1) vmcnt4 -> PH_END(ph8) -> ph1-top
//  bfO(0):  ph4(i-1) -> ph8(i-1) vmcnt4 -> PH_END(ph8) -> end-ph1
//  afO(0):  ph5(i-1) -> ph8(i-1) vmcnt4 -> PH_END(ph8) -> end-ph2
//  afE(1):  ph7(i-1) -> ph3(i) vmcnt2  -> PH_END(ph3) -> end-ph4
//  bfE(1):  ph2(i)   -> ph3(i) vmcnt2  -> PH_END(ph3) -> end-ph4
//  bfO(1):  ph8(i-1) -> ph3(i) vmcnt2  -> PH_END(ph3) -> end-ph5
//  afO(1):  ph1(i)   -> ph3(i) vmcnt2  -> PH_END(ph3) -> end-ph6
//  afE(0):  ph3(i)   -> ph7(i) vmcnt8  -> PH_END(ph7) -> end-ph8 (if pf)
// In-phase write/read disjointness (all waves between same barrier pair):
//  ph1 W:A(b1)p1 R:B(b0)p1 | ph2 W:B(b1)p0 R:A(b0)p1 | ph4 W:B(b0)p1
//  R:A(b1)p0,B(b1)p0 | ph5 W:A(b0)p1 R:B(b1)p1 | ph6 W:B(b0)p0 R:A(b1)p1 |
//  ph8 W:B(b1)p1 R:A(b0)p0.  All disjoint.
// Register WAR: each af/bfE/bfO overwrite follows (in program order) the last
// MFMA that consumes the old value; MFMA latches operands at issue.
// Tail i=17: no stages after ph2; ph3 gate becomes vmcnt(0); later gates are
// no-ops; ph8-end read skipped (pf).
__global__ __launch_bounds__(512, 1)
void conv_mfma(const unsigned short* __restrict__ xp,
               const unsigned short* __restrict__ wb,
               const float* __restrict__ alpha,
               float* __restrict__ out) {
  __shared__ __align__(16) char lds[131072];

  const int tid = threadIdx.x;
  const int wave = tid >> 6, lane = tid & 63;
  const int wm = wave & 1, wn = wave >> 1;          // wn 0..3

  // XCD-chunked pixel-tile swizzle: 392 = 8 XCDs x 49 contiguous tiles
  const int ptile = (blockIdx.x & 7) * 49 + (blockIdx.x >> 3);
  const int pix0 = ptile * 256;

  const int ar = lane & 15, aq = lane >> 4;
  const int rpos = (aq ^ ((ar >> 1) & 3)) * 16;     // fragment-read byte pos
  const int rsub = lane >> 2;
  const int chunkS = (lane & 3) ^ ((rsub >> 1) & 3);  // stage source chunk

  const char* wbB = (const char*)wb;
  const char* xpB = (const char*)xp;

  // ---- stage pointer setup: instr j of this wave covers (ks, 16-row group g)
  const char* aSrc[2]; int aDst[2];
  const char* bSrcP[2][2]; int bDst[2];
#pragma unroll
  for (int j = 0; j < 2; ++j) {
    const int idx = j * 8 + wave;        // 0..15
    const int ksS = idx & 1, grp = idx >> 1;   // grp 0..7
    const int rowNP = (grp & 3) * 16 + ((grp >> 2) << 7);   // A rows, parity 0
    aSrc[j] = wbB + (size_t)(rowNP + rsub) * 4608 + ksS * 64 + chunkS * 16;
    aDst[j] = ksS * 16384 + rowNP * 64;
    const int pixNP = (grp >> 1) * 64 + (grp & 1) * 16;     // B pix, parity 0
#pragma unroll
    for (int par = 0; par < 2; ++par) {
      const int pix = pix0 + pixNP + par * 32 + rsub;
      const int n = pix / 3136, rem = pix % 3136;
      const int h = rem / 56, w = rem % 56;
      bSrcP[par][j] = xpB + (size_t)((n * 58 + h) * 58 + w) * 512 + ksS * 64 + chunkS * 16;
    }
    bDst[j] = 65536 + ksS * 16384 + pixNP * 64;
  }

  f32x4 acc[8][4];
#pragma unroll
  for (int i = 0; i < 8; ++i)
#pragma unroll
    for (int j = 0; j < 4; ++j) acc[i][j] = (f32x4){0.f, 0.f, 0.f, 0.f};

  bf16x8 af[4][2], bfE[2][2], bfO[2][2];

  auto stageA = [&](int b, int T, int par) {
    const size_t so = (size_t)par * 294912 + (size_t)T * 128;
    const int dof = par * 4096 + b * 32768;
#pragma unroll
    for (int j = 0; j < 2; ++j)
      async16(lds + aDst[j] + dof, aSrc[j] + so);
  };
  auto stageB = [&](int b, int T, int par) {
    const int tap = T >> 2;
    const int kh = (tap * 11) >> 5, kw = tap - kh * 3;
    const int ob = (kh * 58 + kw) * 512 + (T & 3) * 128;
    const int dof = par * 2048 + b * 32768;
#pragma unroll
    for (int j = 0; j < 2; ++j)
      async16(lds + bDst[j] + dof, bSrcP[par][j] + ob);
  };
  auto readA = [&](int b, int mh) {
    const char* base = lds + b * 32768;
#pragma unroll
    for (int q = 0; q < 4; ++q)
#pragma unroll
      for (int ks = 0; ks < 2; ++ks)
        af[q][ks] = *(const bf16x8*)(base + ks * 16384 +
                      (wm * 128 + mh * 64 + q * 16 + ar) * 64 + rpos);
  };
  auto readB = [&](int b, int nh, bf16x8 (*bf)[2]) {
    const char* base = lds + 65536 + b * 32768;
#pragma unroll
    for (int q = 0; q < 2; ++q)
#pragma unroll
      for (int ks = 0; ks < 2; ++ks)
        bf[q][ks] = *(const bf16x8*)(base + ks * 16384 +
                      (wn * 64 + nh * 32 + q * 16 + ar) * 64 + rpos);
  };
  auto mmaQ = [&](int mh, int nh, bf16x8 (*bf)[2]) {
    __builtin_amdgcn_s_setprio(1);
#pragma unroll
    for (int ks = 0; ks < 2; ++ks)
#pragma unroll
      for (int q = 0; q < 4; ++q)
#pragma unroll
        for (int r = 0; r < 2; ++r)
          acc[mh * 4 + q][nh * 2 + r] = __builtin_amdgcn_mfma_f32_16x16x32_bf16(
              af[q][ks], bf[r][ks], acc[mh * 4 + q][nh * 2 + r], 0, 0, 0);
    __builtin_amdgcn_s_setprio(0);
    __builtin_amdgcn_sched_barrier(0);   // pin end-of-phase reads after MFMAs
  };

#define PH_SYNC                                          \
  asm volatile("" ::: "memory");                         \
  __builtin_amdgcn_s_barrier();                          \
  asm volatile("s_waitcnt lgkmcnt(0)" ::: "memory");     \
  __builtin_amdgcn_sched_barrier(0);
#define PH_END                                           \
  asm volatile("" ::: "memory");                         \
  __builtin_amdgcn_s_barrier();

  // ---- prologue: tile 0 -> buf0 (4 halves), tile 1 A_even/B_odd -> buf1.
  // vmcnt(4) leaves the last 2 stage-calls outstanding -> tile-0 halves
  // landed (per-wave); PH_END makes it block-wide; then pre-read afE(0).
  stageA(0, 0, 0); stageB(0, 0, 1); stageA(0, 0, 1); stageB(0, 0, 0);
  stageA(1, 1, 0); stageB(1, 1, 1);
  asm volatile("s_waitcnt vmcnt(4)" ::: "memory");
  PH_END;
  readA(0, 0);                     // afE(0) for ph1 of iteration 0

  for (int i = 0; i < 18; ++i) {
    const int T0 = 2 * i, T1 = 2 * i + 1;
    const bool pf = (i < 17);
    // ph1: top-read bfE(0) ; Q(0,0) buf0 ; end-read bfO(0)
    readB(0, 0, bfE);
    stageA(1, T1, 1);
    PH_SYNC; mmaQ(0, 0, bfE);
    readB(0, 1, bfO);
    PH_END;
    // ph2: Q(0,1) ; end-read afO(0)
    stageB(1, T1, 0);
    PH_SYNC; mmaQ(0, 1, bfO);
    readA(0, 1);
    PH_END;
    // ph3: Q(1,1) ; gate for the buf1 read-sets (end-ph4..end-ph6)
    if (pf) stageA(0, T0 + 2, 0);
    PH_SYNC; mmaQ(1, 1, bfO);
    if (pf) { asm volatile("s_waitcnt vmcnt(2)" ::: "memory"); }
    else    { asm volatile("s_waitcnt vmcnt(0)" ::: "memory"); }
    PH_END;
    // ph4: Q(1,0) ; end-reads afE(1)+bfE(1)  [gated ph3+barrier]
    if (pf) stageB(0, T0 + 2, 1);
    PH_SYNC; mmaQ(1, 0, bfE);
    readA(1, 0); readB(1, 0, bfE);
    PH_END;
    // ph5: Q(0,0) buf1 ; end-read bfO(1)
    if (pf) stageA(0, T0 + 2, 1);
    PH_SYNC; mmaQ(0, 0, bfE);
    readB(1, 1, bfO);
    PH_END;
    // ph6: Q(0,1) ; end-read afO(1)
    if (pf) stageB(0, T0 + 2, 0);
    PH_SYNC; mmaQ(0, 1, bfO);
    readA(1, 1);
    PH_END;
    // ph7: Q(1,1) ; gate for end-ph8's afE(0) read
    if (pf) stageA(1, T1 + 2, 0);
    PH_SYNC; mmaQ(1, 1, bfO);
    asm volatile("s_waitcnt vmcnt(8)" ::: "memory");
    PH_END;
    // ph8: Q(1,0) ; end-read afE(0) [gated ph7+barrier] ; vmcnt gate for ph1
    if (pf) stageB(1, T1 + 2, 1);
    PH_SYNC; mmaQ(1, 0, bfE);
    if (pf) readA(0, 0);
    asm volatile("s_waitcnt vmcnt(4)" ::: "memory");
    PH_END;
  }
#undef PH_SYNC
#undef PH_END

  // epilogue: D[row=o][col=pix], col=lane&15, row=(lane>>4)*4+r ; scale alpha
  int nc[4], rc[4];
#pragma unroll
  for (int ni = 0; ni < 4; ++ni) {
    const int pix = pix0 + wn * 64 + ni * 16 + ar;
    nc[ni] = pix / 3136; rc[ni] = pix % 3136;
  }
#pragma unroll
  for (int mi = 0; mi < 8; ++mi) {
    const int orow = wm * 128 + mi * 16 + aq * 4;
    float al[4];
#pragma unroll
    for (int r = 0; r < 4; ++r) al[r] = alpha[orow + r];
#pragma unroll
    for (int ni = 0; ni < 4; ++ni) {
      const size_t base = (size_t)nc[ni] * 802816 + (size_t)orow * 3136 + (size_t)rc[ni];
#pragma unroll
      for (int r = 0; r < 4; ++r)
        out[base + (size_t)r * 3136] = acc[mi][ni][r] * al[r];
    }
  }
}

extern "C" void kernel_launch(void* const* d_in, const int* in_sizes, int n_in,
                              void* d_out, int out_size, void* d_ws, size_t ws_size,
                              hipStream_t stream) {
  const float* x = (const float*)d_in[0];
  const float* w = (const float*)d_in[1];
  char* ws = (char*)d_ws;
  unsigned short* xp  = (unsigned short*)ws;
  unsigned short* wbp = (unsigned short*)(ws + WB_OFF);
  float* alpha = (float*)(ws + AL_OFF);
  float* out = (float*)d_out;

  zero_halo<<<32, 1024, 0, stream>>>(xp);
  prep_w<<<256, 256, 0, stream>>>(w, wbp, alpha);
  prep_x<<<32 * 49, 256, 0, stream>>>(x, xp);
  conv_mfma<<<392, 512, 0, stream>>>(xp, wbp, alpha, out);
}